// Round 2
// baseline (439.226 us; speedup 1.0000x reference)
//
#include <hip/hip_runtime.h>

#define TOK   16384
#define DIM   1024
#define INNER 4096
#define EPSF  1e-5f

typedef int v4i  __attribute__((ext_vector_type(4)));
typedef int v16i __attribute__((ext_vector_type(16)));

static __device__ __forceinline__ void async_copy16(const char* g, char* l) {
    __builtin_amdgcn_global_load_lds(
        (const __attribute__((address_space(1))) unsigned int*)g,
        (__attribute__((address_space(3))) unsigned int*)l, 16, 0, 0);
}

static __device__ __forceinline__ float bf2f(unsigned short u) {
    return __uint_as_float(((unsigned)u) << 16);
}
static __device__ __forceinline__ unsigned short f2bf(float f) {
    unsigned u = __float_as_uint(f);
    return (unsigned short)((u + 0x7fffu + ((u >> 16) & 1u)) >> 16);  // RNE
}

// erf via Abramowitz-Stegun 7.1.26, |abs err| <= 1.5e-7
static __device__ __forceinline__ float fast_erf(float z) {
    float az = fabsf(z);
    float tt = __builtin_amdgcn_rcpf(1.f + 0.3275911f * az);
    float poly = ((((1.061405429f * tt - 1.453152027f) * tt + 1.421413741f) * tt
                   - 0.284496736f) * tt + 0.254829592f) * tt;
    float er = 1.f - poly * __expf(-az * az);
    return copysignf(er, z);
}
static __device__ __forceinline__ float gelu_exact(float v) {
    return 0.5f * v * (1.f + fast_erf(v * 0.70710678118654752f));
}

static __device__ __forceinline__ float waveSum(float v) {
#pragma unroll
    for (int o = 32; o > 0; o >>= 1) v += __shfl_down(v, o, 64);
    return v;
}
static __device__ __forceinline__ float waveMax(float v) {
#pragma unroll
    for (int o = 32; o > 0; o >>= 1) v = fmaxf(v, __shfl_down(v, o, 64));
    return v;
}

// ---- per-tensor sum(|w|) reduction (f32 in) ----
__global__ void absmean_k(const float* __restrict__ w, int n4, float* __restrict__ acc) {
    int idx = blockIdx.x * blockDim.x + threadIdx.x;
    int stride = gridDim.x * blockDim.x;
    const float4* w4 = (const float4*)w;
    float s = 0.f;
    for (int i = idx; i < n4; i += stride) {
        float4 v = w4[i];
        s += fabsf(v.x) + fabsf(v.y) + fabsf(v.z) + fabsf(v.w);
    }
    __shared__ float sp[4];
    int wv = threadIdx.x >> 6, lane = threadIdx.x & 63;
    s = waveSum(s);
    if (lane == 0) sp[wv] = s;
    __syncthreads();
    if (threadIdx.x == 0) atomicAdd(acc, sp[0] + sp[1] + sp[2] + sp[3]);
}

// ---- per-tensor ternary quantize: wq = clip(round(w/clip(mean|w|,eps)),-1,1) ----
__global__ void wquant_k(const float* __restrict__ w, int n,
                         const float* __restrict__ acc, float* __restrict__ wscale,
                         char* __restrict__ wq) {
    float mean = *acc / (float)n;
    float cl = fmaxf(mean, EPSF);
    float s = 1.f / cl;
    if (blockIdx.x == 0 && threadIdx.x == 0) *wscale = cl;  // dequant factor
    int idx = blockIdx.x * blockDim.x + threadIdx.x;
    int stride = gridDim.x * blockDim.x;
    int n4 = n >> 2;
    const float4* w4 = (const float4*)w;
    unsigned* q4 = (unsigned*)wq;
    for (int i = idx; i < n4; i += stride) {
        float4 v = w4[i];
        float e[4] = {v.x, v.y, v.z, v.w};
        unsigned packed = 0;
#pragma unroll
        for (int j = 0; j < 4; j++) {
            float r = rintf(e[j] * s);
            r = fminf(fmaxf(r, -1.f), 1.f);
            packed |= ((unsigned)((int)r & 0xff)) << (8 * j);
        }
        q4[i] = packed;
    }
}

// ---- RMSNorm + per-token absmax int8 quant, f32 input. One block per row. ----
template <int D, int VPT>
__global__ void actquant_f32_k(const float* __restrict__ X, char* __restrict__ Q,
                               float* __restrict__ rs_out) {
    int token = blockIdx.x;
    int t = threadIdx.x;
    const float4* xp = (const float4*)(X + (long)token * D);
    float vals[VPT];
    float ss = 0.f, am = 0.f;
#pragma unroll
    for (int j = 0; j < VPT / 4; j++) {
        float4 v = xp[t * (VPT / 4) + j];
        vals[4 * j] = v.x; vals[4 * j + 1] = v.y; vals[4 * j + 2] = v.z; vals[4 * j + 3] = v.w;
        ss += v.x * v.x + v.y * v.y + v.z * v.z + v.w * v.w;
        am = fmaxf(am, fmaxf(fmaxf(fabsf(v.x), fabsf(v.y)), fmaxf(fabsf(v.z), fabsf(v.w))));
    }
    __shared__ float sp[8];
    __shared__ float bc[2];
    int wv = t >> 6, lane = t & 63;
    float S = waveSum(ss);
    float M = waveMax(am);
    if (lane == 0) { sp[wv] = S; sp[4 + wv] = M; }
    __syncthreads();
    if (t == 0) {
        float Sa = sp[0] + sp[1] + sp[2] + sp[3];
        float Ma = fmaxf(fmaxf(sp[4], sp[5]), fmaxf(sp[6], sp[7]));
        float rinv = rsqrtf(Sa * (1.f / (float)D) + EPSF);   // rsqrt(mean(x^2)+eps)
        float amn = Ma * rinv;                                // absmax of normalized row
        float scale = 127.f / fmaxf(amn, EPSF);
        rs_out[token] = 1.f / scale;                          // dequant factor
        bc[0] = rinv; bc[1] = scale;
    }
    __syncthreads();
    float rinv = bc[0], scale = bc[1];
    unsigned outw[VPT / 4];
#pragma unroll
    for (int j = 0; j < VPT; j++) {
        float r = rintf((vals[j] * rinv) * scale);
        r = fminf(fmaxf(r, -128.f), 127.f);
        unsigned qi = (unsigned)((int)r & 0xff) << (8 * (j & 3));
        if ((j & 3) == 0) outw[j / 4] = qi; else outw[j / 4] |= qi;
    }
    unsigned* qp = (unsigned*)(Q + (long)token * D);
#pragma unroll
    for (int j = 0; j < VPT / 4; j++) qp[t * (VPT / 4) + j] = outw[j];
}

// ---- GELU + RMSNorm + int8 quant, bf16 input (pre-activation h). ----
// GELU lives here (HBM-bound stream, VALU headroom) instead of GEMM1's epilogue.
template <int D, int VPT>  // VPT must be 16
__global__ void actquant_bf16_k(const unsigned short* __restrict__ X, char* __restrict__ Q,
                                float* __restrict__ rs_out) {
    int token = blockIdx.x;
    int t = threadIdx.x;
    const uint4* xp = (const uint4*)(X + (long)token * D);
    float vals[VPT];
    float ss = 0.f, am = 0.f;
#pragma unroll
    for (int j = 0; j < VPT / 8; j++) {
        uint4 v = xp[t * (VPT / 8) + j];
        unsigned ws[4] = {v.x, v.y, v.z, v.w};
#pragma unroll
        for (int p = 0; p < 4; p++) {
            float f0 = gelu_exact(bf2f((unsigned short)(ws[p] & 0xffff)));
            float f1 = gelu_exact(bf2f((unsigned short)(ws[p] >> 16)));
            vals[8 * j + 2 * p] = f0; vals[8 * j + 2 * p + 1] = f1;
            ss += f0 * f0 + f1 * f1;
            am = fmaxf(am, fmaxf(fabsf(f0), fabsf(f1)));
        }
    }
    __shared__ float sp[8];
    __shared__ float bc[2];
    int wv = t >> 6, lane = t & 63;
    float S = waveSum(ss);
    float M = waveMax(am);
    if (lane == 0) { sp[wv] = S; sp[4 + wv] = M; }
    __syncthreads();
    if (t == 0) {
        float Sa = sp[0] + sp[1] + sp[2] + sp[3];
        float Ma = fmaxf(fmaxf(sp[4], sp[5]), fmaxf(sp[6], sp[7]));
        float rinv = rsqrtf(Sa * (1.f / (float)D) + EPSF);
        float amn = Ma * rinv;
        float scale = 127.f / fmaxf(amn, EPSF);
        rs_out[token] = 1.f / scale;
        bc[0] = rinv; bc[1] = scale;
    }
    __syncthreads();
    float rinv = bc[0], scale = bc[1];
    unsigned outw[4];
#pragma unroll
    for (int j = 0; j < VPT; j++) {
        float r = rintf((vals[j] * rinv) * scale);
        r = fminf(fmaxf(r, -128.f), 127.f);
        unsigned qi = (unsigned)((int)r & 0xff) << (8 * (j & 3));
        if ((j & 3) == 0) outw[j / 4] = qi; else outw[j / 4] |= qi;
    }
    uint4* qp = (uint4*)(Q + (long)token * D);
    qp[t] = make_uint4(outw[0], outw[1], outw[2], outw[3]);
}

// ---- int8 GEMM, 256x256 tile, BK=128, 8 waves (2M x 4N), 4-phase, K-major LDS ----
// LDS layout per tile: [kslot 0..7][row 0..255][16B] (k-slot planes of 4 KB).
// A fragment read (fixed kslot, 32 consecutive rows) = contiguous 512 B per
// 32-lane half-wave -> conflict-free BY CONSTRUCTION (same shape as the linear
// global_load_lds write). No XOR swizzle; the permutation lives in the staging
// SOURCE address (thread t fetches the global chunk for its linear LDS slot).
//
// Schedule (T3+T4+T5): 4 phases per K-tile, one per kstep(32):
//   phase ks: { 6 ds_read_b128 (a[4],b[2]) ; 2 global_load_lds ; barrier ;
//               setprio(1) ; 8 MFMA ; setprio(0) ; [vmcnt] ; barrier }
// Staging ring splits along K: phases 0,1 stage T+1's k-half0 (A then B),
// phases 2,3 stage k-half1. Counted waits, never 0 in steady state:
//   end of phase 1: vmcnt(4)  -> T's k-half1 (issued T-1 p2,p3) landed
//   end of phase 3: vmcnt(4)  -> T+1's k-half0 landed, k-half1 in flight
// 24 ds_reads / 32 MFMA per tile per wave = 0.75 KB/MFMA: LDS pipe (2000 cyc/CU
// /tile incl. writes) < MFMA (2330 cyc) -> matrix pipe is the long pole.
template <int OUT_F32>
__global__ __launch_bounds__(512, 2) void gemm8_k(
    const char* __restrict__ A, const char* __restrict__ Bw,
    const float* __restrict__ rs, const float* __restrict__ wscale_p,
    const float* __restrict__ bias, void* __restrict__ outp,
    int M, int N, int K) {
    __shared__ char L[131072];  // 2 bufs x { A 32KB | B 32KB } in k-slot-major form
    int t = threadIdx.x;
    int lane = t & 63, wv = t >> 6;
    int l31 = lane & 31, kh = lane >> 5;
    int wmi = wv >> 2, wni = wv & 3;  // wave tile: rows wmi*128+[0,128), cols wni*64+[0,64)
    int m0 = blockIdx.y * 256, n0 = blockIdx.x * 256;

    // staging: thread t owns rows (t&255), k-slot base (t>>8); LDS dst is linear t*16
    // within each (buf, matrix, k-half) region; u in {0,1} adds 2 k-slots (+8 KB / +32 B).
    const char* srcA0 = A  + (long)(m0 + (t & 255)) * K + ((t >> 8) * 16);
    const char* srcB0 = Bw + (long)(n0 + (t & 255)) * K + ((t >> 8) * 16);
    char* dA = L + (size_t)t * 16;
    char* dB = L + 32768 + (size_t)t * 16;

    auto stA = [&](int Tt, int kb) {
        const char* g = srcA0 + ((long)Tt << 7) + kb * 64;
        char* l = dA + (Tt & 1) * 65536 + kb * 16384;
        async_copy16(g, l);
        async_copy16(g + 32, l + 8192);
    };
    auto stB = [&](int Tt, int kb) {
        const char* g = srcB0 + ((long)Tt << 7) + kb * 64;
        char* l = dB + (Tt & 1) * 65536 + kb * 16384;
        async_copy16(g, l);
        async_copy16(g + 32, l + 8192);
    };

    // fragment read bases: kslot plane (2ks+kh)*4096, row*16
    const char* rdA = L + kh * 4096 + (size_t)(wmi * 128 + l31) * 16;
    const char* rdB = L + 32768 + kh * 4096 + (size_t)(wni * 64 + l31) * 16;

    v16i acc[4][2] = {};
    int nK = K >> 7;

    // prologue: T0 all 4 half-stages; oldest 4 (k-half0) drained, k-half1 in flight
    stA(0, 0); stB(0, 0); stA(0, 1); stB(0, 1);
    asm volatile("s_waitcnt vmcnt(4)" ::: "memory");
    __builtin_amdgcn_s_barrier();

    for (int T = 0; T < nK; ++T) {
        int bo = (T & 1) * 65536;
        bool pre = (T + 1 < nK);
#pragma unroll
        for (int ks = 0; ks < 4; ++ks) {
            const char* pa = rdA + bo + ks * 8192;
            const char* pb = rdB + bo + ks * 8192;
            v4i a0 = *(const v4i*)(pa);
            v4i a1 = *(const v4i*)(pa + 512);
            v4i a2 = *(const v4i*)(pa + 1024);
            v4i a3 = *(const v4i*)(pa + 1536);
            v4i b0 = *(const v4i*)(pb);
            v4i b1 = *(const v4i*)(pb + 512);
            if (pre) {
                if (ks == 0) stA(T + 1, 0);
                else if (ks == 1) stB(T + 1, 0);
                else if (ks == 2) stA(T + 1, 1);
                else stB(T + 1, 1);
            }
            __builtin_amdgcn_s_barrier();
            __builtin_amdgcn_s_setprio(1);
            acc[0][0] = __builtin_amdgcn_mfma_i32_32x32x32_i8(a0, b0, acc[0][0], 0, 0, 0);
            acc[0][1] = __builtin_amdgcn_mfma_i32_32x32x32_i8(a0, b1, acc[0][1], 0, 0, 0);
            acc[1][0] = __builtin_amdgcn_mfma_i32_32x32x32_i8(a1, b0, acc[1][0], 0, 0, 0);
            acc[1][1] = __builtin_amdgcn_mfma_i32_32x32x32_i8(a1, b1, acc[1][1], 0, 0, 0);
            acc[2][0] = __builtin_amdgcn_mfma_i32_32x32x32_i8(a2, b0, acc[2][0], 0, 0, 0);
            acc[2][1] = __builtin_amdgcn_mfma_i32_32x32x32_i8(a2, b1, acc[2][1], 0, 0, 0);
            acc[3][0] = __builtin_amdgcn_mfma_i32_32x32x32_i8(a3, b0, acc[3][0], 0, 0, 0);
            acc[3][1] = __builtin_amdgcn_mfma_i32_32x32x32_i8(a3, b1, acc[3][1], 0, 0, 0);
            __builtin_amdgcn_s_setprio(0);
            if (ks == 1) {
                if (pre) asm volatile("s_waitcnt vmcnt(4)" ::: "memory");
                else     asm volatile("s_waitcnt vmcnt(0)" ::: "memory");
            }
            if (ks == 3 && pre) asm volatile("s_waitcnt vmcnt(4)" ::: "memory");
            __builtin_amdgcn_s_barrier();
        }
    }

    // Epilogue. 32x32 C/D layout: col = lane&31, row = (reg&3) + 8*(reg>>2) + 4*(lane>>5)
    float wsc = *wscale_p;
    float bv[2];
#pragma unroll
    for (int j = 0; j < 2; j++) bv[j] = bias[n0 + wni * 64 + j * 32 + l31];
#pragma unroll
    for (int i = 0; i < 4; i++) {
        int mbase = m0 + wmi * 128 + i * 32 + 4 * kh;
        float fsv[16];
#pragma unroll
        for (int rg = 0; rg < 16; rg++)
            fsv[rg] = rs[mbase + (rg & 3) + 8 * (rg >> 2)] * wsc;
#pragma unroll
        for (int j = 0; j < 2; j++) {
            int ng = n0 + wni * 64 + j * 32 + l31;
#pragma unroll
            for (int rg = 0; rg < 16; rg++) {
                int mg = mbase + (rg & 3) + 8 * (rg >> 2);
                float v = (float)acc[i][j][rg] * fsv[rg] + bv[j];
                long idx = (long)mg * N + ng;
                if (OUT_F32) ((float*)outp)[idx] = v;
                else ((unsigned short*)outp)[idx] = f2bf(v);
            }
        }
    }
}

extern "C" void kernel_launch(void* const* d_in, const int* in_sizes, int n_in,
                              void* d_out, int out_size, void* d_ws, size_t ws_size,
                              hipStream_t stream) {
    const float* x  = (const float*)d_in[0];
    const float* w1 = (const float*)d_in[1];
    const float* b1 = (const float*)d_in[2];
    const float* w2 = (const float*)d_in[3];
    const float* b2 = (const float*)d_in[4];
    float* out = (float*)d_out;

    char* ws = (char*)d_ws;
    float* acc1 = (float*)(ws + 0);
    float* acc2 = (float*)(ws + 4);
    float* wsc1 = (float*)(ws + 8);
    float* wsc2 = (float*)(ws + 12);
    size_t off = 256;
    char* w1q = ws + off; off += (size_t)INNER * DIM;        // 4 MB
    char* w2q = ws + off; off += (size_t)INNER * DIM;        // 4 MB
    char* xq1 = ws + off; off += (size_t)TOK * DIM;          // 16 MB
    float* rs1 = (float*)(ws + off); off += (size_t)TOK * 4; // 64 KB
    char* xq2 = ws + off; off += (size_t)TOK * INNER;        // 64 MB
    float* rs2 = (float*)(ws + off); off += (size_t)TOK * 4; // 64 KB
    unsigned short* h = (unsigned short*)(ws + off);         // 128 MB bf16 (pre-GELU)

    hipMemsetAsync(d_ws, 0, 16, stream);

    int nw = INNER * DIM;
    absmean_k<<<1024, 256, 0, stream>>>(w1, nw / 4, acc1);
    absmean_k<<<1024, 256, 0, stream>>>(w2, nw / 4, acc2);
    wquant_k<<<2048, 256, 0, stream>>>(w1, nw, acc1, wsc1, w1q);
    wquant_k<<<2048, 256, 0, stream>>>(w2, nw, acc2, wsc2, w2q);

    actquant_f32_k<DIM, 4><<<TOK, 256, 0, stream>>>(x, xq1, rs1);
    gemm8_k<0><<<dim3(INNER / 256, TOK / 256), 512, 0, stream>>>(
        xq1, w1q, rs1, wsc1, b1, (void*)h, TOK, INNER, DIM);
    actquant_bf16_k<INNER, 16><<<TOK, 256, 0, stream>>>(h, xq2, rs2);
    gemm8_k<1><<<dim3(DIM / 256, TOK / 256), 512, 0, stream>>>(
        xq2, w2q, rs2, wsc2, b2, (void*)out, TOK, DIM, INNER);
}

// Round 3
// 438.598 us; speedup vs baseline: 1.0014x; 1.0014x over previous
//
#include <hip/hip_runtime.h>

#define TOK   16384
#define DIM   1024
#define INNER 4096
#define EPSF  1e-5f

typedef int v4i  __attribute__((ext_vector_type(4)));
typedef int v16i __attribute__((ext_vector_type(16)));

static __device__ __forceinline__ void async_copy16(const char* g, char* l) {
    __builtin_amdgcn_global_load_lds(
        (const __attribute__((address_space(1))) unsigned int*)g,
        (__attribute__((address_space(3))) unsigned int*)l, 16, 0, 0);
}

static __device__ __forceinline__ float bf2f(unsigned short u) {
    return __uint_as_float(((unsigned)u) << 16);
}
static __device__ __forceinline__ unsigned short f2bf(float f) {
    unsigned u = __float_as_uint(f);
    return (unsigned short)((u + 0x7fffu + ((u >> 16) & 1u)) >> 16);  // RNE
}

// erf via Abramowitz-Stegun 7.1.26, |abs err| <= 1.5e-7
static __device__ __forceinline__ float fast_erf(float z) {
    float az = fabsf(z);
    float tt = __builtin_amdgcn_rcpf(1.f + 0.3275911f * az);
    float poly = ((((1.061405429f * tt - 1.453152027f) * tt + 1.421413741f) * tt
                   - 0.284496736f) * tt + 0.254829592f) * tt;
    float er = 1.f - poly * __expf(-az * az);
    return copysignf(er, z);
}
static __device__ __forceinline__ float gelu_exact(float v) {
    return 0.5f * v * (1.f + fast_erf(v * 0.70710678118654752f));
}

static __device__ __forceinline__ float waveSum(float v) {
#pragma unroll
    for (int o = 32; o > 0; o >>= 1) v += __shfl_down(v, o, 64);
    return v;
}
static __device__ __forceinline__ float waveMax(float v) {
#pragma unroll
    for (int o = 32; o > 0; o >>= 1) v = fmaxf(v, __shfl_down(v, o, 64));
    return v;
}

// ---- per-tensor sum(|w|) reduction (f32 in) ----
__global__ void absmean_k(const float* __restrict__ w, int n4, float* __restrict__ acc) {
    int idx = blockIdx.x * blockDim.x + threadIdx.x;
    int stride = gridDim.x * blockDim.x;
    const float4* w4 = (const float4*)w;
    float s = 0.f;
    for (int i = idx; i < n4; i += stride) {
        float4 v = w4[i];
        s += fabsf(v.x) + fabsf(v.y) + fabsf(v.z) + fabsf(v.w);
    }
    __shared__ float sp[4];
    int wv = threadIdx.x >> 6, lane = threadIdx.x & 63;
    s = waveSum(s);
    if (lane == 0) sp[wv] = s;
    __syncthreads();
    if (threadIdx.x == 0) atomicAdd(acc, sp[0] + sp[1] + sp[2] + sp[3]);
}

// ---- per-tensor ternary quantize: wq = clip(round(w/clip(mean|w|,eps)),-1,1) ----
__global__ void wquant_k(const float* __restrict__ w, int n,
                         const float* __restrict__ acc, float* __restrict__ wscale,
                         char* __restrict__ wq) {
    float mean = *acc / (float)n;
    float cl = fmaxf(mean, EPSF);
    float s = 1.f / cl;
    if (blockIdx.x == 0 && threadIdx.x == 0) *wscale = cl;  // dequant factor
    int idx = blockIdx.x * blockDim.x + threadIdx.x;
    int stride = gridDim.x * blockDim.x;
    int n4 = n >> 2;
    const float4* w4 = (const float4*)w;
    unsigned* q4 = (unsigned*)wq;
    for (int i = idx; i < n4; i += stride) {
        float4 v = w4[i];
        float e[4] = {v.x, v.y, v.z, v.w};
        unsigned packed = 0;
#pragma unroll
        for (int j = 0; j < 4; j++) {
            float r = rintf(e[j] * s);
            r = fminf(fmaxf(r, -1.f), 1.f);
            packed |= ((unsigned)((int)r & 0xff)) << (8 * j);
        }
        q4[i] = packed;
    }
}

// ---- RMSNorm + per-token absmax int8 quant, f32 input. One block per row. ----
template <int D, int VPT>
__global__ void actquant_f32_k(const float* __restrict__ X, char* __restrict__ Q,
                               float* __restrict__ rs_out) {
    int token = blockIdx.x;
    int t = threadIdx.x;
    const float4* xp = (const float4*)(X + (long)token * D);
    float vals[VPT];
    float ss = 0.f, am = 0.f;
#pragma unroll
    for (int j = 0; j < VPT / 4; j++) {
        float4 v = xp[t * (VPT / 4) + j];
        vals[4 * j] = v.x; vals[4 * j + 1] = v.y; vals[4 * j + 2] = v.z; vals[4 * j + 3] = v.w;
        ss += v.x * v.x + v.y * v.y + v.z * v.z + v.w * v.w;
        am = fmaxf(am, fmaxf(fmaxf(fabsf(v.x), fabsf(v.y)), fmaxf(fabsf(v.z), fabsf(v.w))));
    }
    __shared__ float sp[8];
    __shared__ float bc[2];
    int wv = t >> 6, lane = t & 63;
    float S = waveSum(ss);
    float M = waveMax(am);
    if (lane == 0) { sp[wv] = S; sp[4 + wv] = M; }
    __syncthreads();
    if (t == 0) {
        float Sa = sp[0] + sp[1] + sp[2] + sp[3];
        float Ma = fmaxf(fmaxf(sp[4], sp[5]), fmaxf(sp[6], sp[7]));
        float rinv = rsqrtf(Sa * (1.f / (float)D) + EPSF);   // rsqrt(mean(x^2)+eps)
        float amn = Ma * rinv;                                // absmax of normalized row
        float scale = 127.f / fmaxf(amn, EPSF);
        rs_out[token] = 1.f / scale;                          // dequant factor
        bc[0] = rinv; bc[1] = scale;
    }
    __syncthreads();
    float rinv = bc[0], scale = bc[1];
    unsigned outw[VPT / 4];
#pragma unroll
    for (int j = 0; j < VPT; j++) {
        float r = rintf((vals[j] * rinv) * scale);
        r = fminf(fmaxf(r, -128.f), 127.f);
        unsigned qi = (unsigned)((int)r & 0xff) << (8 * (j & 3));
        if ((j & 3) == 0) outw[j / 4] = qi; else outw[j / 4] |= qi;
    }
    unsigned* qp = (unsigned*)(Q + (long)token * D);
#pragma unroll
    for (int j = 0; j < VPT / 4; j++) qp[t * (VPT / 4) + j] = outw[j];
}

// ---- GELU + RMSNorm + int8 quant, bf16 input (pre-activation h). ----
template <int D, int VPT>  // VPT must be 16
__global__ void actquant_bf16_k(const unsigned short* __restrict__ X, char* __restrict__ Q,
                                float* __restrict__ rs_out) {
    int token = blockIdx.x;
    int t = threadIdx.x;
    const uint4* xp = (const uint4*)(X + (long)token * D);
    float vals[VPT];
    float ss = 0.f, am = 0.f;
#pragma unroll
    for (int j = 0; j < VPT / 8; j++) {
        uint4 v = xp[t * (VPT / 8) + j];
        unsigned ws[4] = {v.x, v.y, v.z, v.w};
#pragma unroll
        for (int p = 0; p < 4; p++) {
            float f0 = gelu_exact(bf2f((unsigned short)(ws[p] & 0xffff)));
            float f1 = gelu_exact(bf2f((unsigned short)(ws[p] >> 16)));
            vals[8 * j + 2 * p] = f0; vals[8 * j + 2 * p + 1] = f1;
            ss += f0 * f0 + f1 * f1;
            am = fmaxf(am, fmaxf(fabsf(f0), fabsf(f1)));
        }
    }
    __shared__ float sp[8];
    __shared__ float bc[2];
    int wv = t >> 6, lane = t & 63;
    float S = waveSum(ss);
    float M = waveMax(am);
    if (lane == 0) { sp[wv] = S; sp[4 + wv] = M; }
    __syncthreads();
    if (t == 0) {
        float Sa = sp[0] + sp[1] + sp[2] + sp[3];
        float Ma = fmaxf(fmaxf(sp[4], sp[5]), fmaxf(sp[6], sp[7]));
        float rinv = rsqrtf(Sa * (1.f / (float)D) + EPSF);
        float amn = Ma * rinv;
        float scale = 127.f / fmaxf(amn, EPSF);
        rs_out[token] = 1.f / scale;
        bc[0] = rinv; bc[1] = scale;
    }
    __syncthreads();
    float rinv = bc[0], scale = bc[1];
    unsigned outw[4];
#pragma unroll
    for (int j = 0; j < VPT; j++) {
        float r = rintf((vals[j] * rinv) * scale);
        r = fminf(fmaxf(r, -128.f), 127.f);
        unsigned qi = (unsigned)((int)r & 0xff) << (8 * (j & 3));
        if ((j & 3) == 0) outw[j / 4] = qi; else outw[j / 4] |= qi;
    }
    uint4* qp = (uint4*)(Q + (long)token * D);
    qp[t] = make_uint4(outw[0], outw[1], outw[2], outw[3]);
}

// ---- int8 GEMM: 256x128 tile, BK=64, 256 thr (4 waves, 2Mx2N), wave tile 128x64 ----
// STRIPE LDS layout: stripe = 16 rows x 64 B = 1024 B; within stripe the byte
// position of (row, 16B-slot) is slot*256 + (row&15)*16 == lane*16 for the
// staging lane (slot=lane>>4, row=lane&15). So a LINEAR global_load_lds dest IS
// the stripe layout: source stays row-major (16 rows x 64 B contiguous per wave,
// coalesced) AND fragment reads (fixed slot, 32 rows) are 2x256B contiguous runs
// -> ~0 bank conflicts. Both sides conflict-free, no XOR swizzle.
//
// Concurrency: 48 KB LDS + 256 thr -> >=2 independent blocks/CU. Hazards exist
// only at K-tile boundaries (per-tile double buffer), so ONE barrier per K-tile
// (16 MFMA/wave between barriers); the sibling block fills vmcnt/barrier stalls.
// XCD-chunked blockIdx swizzle keeps A-panel sharers on one L2.
template <int OUT_F32>
__global__ __launch_bounds__(256, 2) void gemm4_k(
    const char* __restrict__ A, const char* __restrict__ Bw,
    const float* __restrict__ rs, const float* __restrict__ wscale_p,
    const float* __restrict__ bias, void* __restrict__ outp,
    int M, int N, int K) {
    __shared__ char L[49152];  // A: 2 x 16 KB at 0; B: 2 x 8 KB at 32768
    int t = threadIdx.x;
    int lane = t & 63, wv = t >> 6;
    int l31 = lane & 31, kh = lane >> 5;
    int wmi = wv >> 1, wni = wv & 1;  // wave tile rows wmi*128+[0,128), cols wni*64+[0,64)

    // XCD-chunked swizzle (grid sizes are multiples of 8)
    int gx = gridDim.x;
    int nwg = gx * gridDim.y;
    int bid = blockIdx.y * gx + blockIdx.x;
    int swz = (bid & 7) * (nwg >> 3) + (bid >> 3);
    int bx = swz % gx, by = swz / gx;
    int m0 = by * 256, n0 = bx * 128;

    // staging: call q covers stripes q*4+wv (rows q*64 + wv*16 + (lane&15)),
    // lane's 16B chunk at global col (lane>>4)*16; LDS dest linear lane*16.
    const char* srcA = A  + (long)(m0 + wv * 16 + (lane & 15)) * K + ((lane >> 4) * 16);
    const char* srcB = Bw + (long)(n0 + wv * 16 + (lane & 15)) * K + ((lane >> 4) * 16);
    char* dstA = L + wv * 1024 + lane * 16;
    char* dstB = L + 32768 + wv * 1024 + lane * 16;

    auto stA = [&](int Tt, int q) {  // q in 0..3
        async_copy16(srcA + (long)q * 64 * K + ((long)Tt << 6),
                     dstA + (Tt & 1) * 16384 + q * 4096);
    };
    auto stB = [&](int Tt, int q) {  // q in 0..1
        async_copy16(srcB + (long)q * 64 * K + ((long)Tt << 6),
                     dstB + (Tt & 1) * 8192 + q * 4096);
    };

    // fragment read offsets: off(row) = (row>>4)*1024 + (row&15)*16, + slot*256
    int offA[4], offB[2];
#pragma unroll
    for (int i = 0; i < 4; i++) {
        int r = wmi * 128 + i * 32 + l31;
        offA[i] = (r >> 4) * 1024 + (r & 15) * 16 + kh * 256;
    }
#pragma unroll
    for (int j = 0; j < 2; j++) {
        int r = wni * 64 + j * 32 + l31;
        offB[j] = (r >> 4) * 1024 + (r & 15) * 16 + kh * 256;
    }

    v16i acc[4][2] = {};
    int nK = K >> 6;

    // prologue: full T0 stage (6 loads/thread), drain, barrier
    stA(0, 0); stA(0, 1); stA(0, 2); stA(0, 3); stB(0, 0); stB(0, 1);
    asm volatile("s_waitcnt vmcnt(0)" ::: "memory");
    asm volatile("s_barrier" ::: "memory");

    for (int T = 0; T < nK; ++T) {
        const char* pA = L + (T & 1) * 16384;
        const char* pB = L + 32768 + (T & 1) * 8192;
        bool pre = (T + 1 < nK);
#pragma unroll
        for (int ks = 0; ks < 2; ++ks) {
            v4i a0 = *(const v4i*)(pA + offA[0] + ks * 512);
            v4i a1 = *(const v4i*)(pA + offA[1] + ks * 512);
            v4i a2 = *(const v4i*)(pA + offA[2] + ks * 512);
            v4i a3 = *(const v4i*)(pA + offA[3] + ks * 512);
            v4i b0 = *(const v4i*)(pB + offB[0] + ks * 512);
            v4i b1 = *(const v4i*)(pB + offB[1] + ks * 512);
            if (pre) {
                if (ks == 0) { stA(T + 1, 0); stA(T + 1, 1); stB(T + 1, 0); }
                else         { stA(T + 1, 2); stA(T + 1, 3); stB(T + 1, 1); }
            }
            __builtin_amdgcn_s_setprio(1);
            acc[0][0] = __builtin_amdgcn_mfma_i32_32x32x32_i8(a0, b0, acc[0][0], 0, 0, 0);
            acc[0][1] = __builtin_amdgcn_mfma_i32_32x32x32_i8(a0, b1, acc[0][1], 0, 0, 0);
            acc[1][0] = __builtin_amdgcn_mfma_i32_32x32x32_i8(a1, b0, acc[1][0], 0, 0, 0);
            acc[1][1] = __builtin_amdgcn_mfma_i32_32x32x32_i8(a1, b1, acc[1][1], 0, 0, 0);
            acc[2][0] = __builtin_amdgcn_mfma_i32_32x32x32_i8(a2, b0, acc[2][0], 0, 0, 0);
            acc[2][1] = __builtin_amdgcn_mfma_i32_32x32x32_i8(a2, b1, acc[2][1], 0, 0, 0);
            acc[3][0] = __builtin_amdgcn_mfma_i32_32x32x32_i8(a3, b0, acc[3][0], 0, 0, 0);
            acc[3][1] = __builtin_amdgcn_mfma_i32_32x32x32_i8(a3, b1, acc[3][1], 0, 0, 0);
            __builtin_amdgcn_s_setprio(0);
        }
        // tile boundary: next tile's buffer fully landed (own loads), then sync
        asm volatile("s_waitcnt vmcnt(0)" ::: "memory");
        asm volatile("s_barrier" ::: "memory");
    }

    // Epilogue. 32x32 C/D layout: col = lane&31, row = (reg&3) + 8*(reg>>2) + 4*(lane>>5)
    float wsc = *wscale_p;
    float bv[2];
#pragma unroll
    for (int j = 0; j < 2; j++) bv[j] = bias[n0 + wni * 64 + j * 32 + l31];
#pragma unroll
    for (int i = 0; i < 4; i++) {
        int mbase = m0 + wmi * 128 + i * 32 + 4 * kh;
        float fsv[16];
#pragma unroll
        for (int rg = 0; rg < 16; rg++)
            fsv[rg] = rs[mbase + (rg & 3) + 8 * (rg >> 2)] * wsc;
#pragma unroll
        for (int j = 0; j < 2; j++) {
            int ng = n0 + wni * 64 + j * 32 + l31;
#pragma unroll
            for (int rg = 0; rg < 16; rg++) {
                int mg = mbase + (rg & 3) + 8 * (rg >> 2);
                float v = (float)acc[i][j][rg] * fsv[rg] + bv[j];
                long idx = (long)mg * N + ng;
                if (OUT_F32) ((float*)outp)[idx] = v;
                else ((unsigned short*)outp)[idx] = f2bf(v);
            }
        }
    }
}

extern "C" void kernel_launch(void* const* d_in, const int* in_sizes, int n_in,
                              void* d_out, int out_size, void* d_ws, size_t ws_size,
                              hipStream_t stream) {
    const float* x  = (const float*)d_in[0];
    const float* w1 = (const float*)d_in[1];
    const float* b1 = (const float*)d_in[2];
    const float* w2 = (const float*)d_in[3];
    const float* b2 = (const float*)d_in[4];
    float* out = (float*)d_out;

    char* ws = (char*)d_ws;
    float* acc1 = (float*)(ws + 0);
    float* acc2 = (float*)(ws + 4);
    float* wsc1 = (float*)(ws + 8);
    float* wsc2 = (float*)(ws + 12);
    size_t off = 256;
    char* w1q = ws + off; off += (size_t)INNER * DIM;        // 4 MB
    char* w2q = ws + off; off += (size_t)INNER * DIM;        // 4 MB
    char* xq1 = ws + off; off += (size_t)TOK * DIM;          // 16 MB
    float* rs1 = (float*)(ws + off); off += (size_t)TOK * 4; // 64 KB
    char* xq2 = ws + off; off += (size_t)TOK * INNER;        // 64 MB
    float* rs2 = (float*)(ws + off); off += (size_t)TOK * 4; // 64 KB
    unsigned short* h = (unsigned short*)(ws + off);         // 128 MB bf16 (pre-GELU)

    hipMemsetAsync(d_ws, 0, 16, stream);

    int nw = INNER * DIM;
    absmean_k<<<1024, 256, 0, stream>>>(w1, nw / 4, acc1);
    absmean_k<<<1024, 256, 0, stream>>>(w2, nw / 4, acc2);
    wquant_k<<<2048, 256, 0, stream>>>(w1, nw, acc1, wsc1, w1q);
    wquant_k<<<2048, 256, 0, stream>>>(w2, nw, acc2, wsc2, w2q);

    actquant_f32_k<DIM, 4><<<TOK, 256, 0, stream>>>(x, xq1, rs1);
    gemm4_k<0><<<dim3(INNER / 128, TOK / 256), 256, 0, stream>>>(
        xq1, w1q, rs1, wsc1, b1, (void*)h, TOK, INNER, DIM);
    actquant_bf16_k<INNER, 16><<<TOK, 256, 0, stream>>>(h, xq2, rs2);
    gemm4_k<1><<<dim3(DIM / 128, TOK / 256), 256, 0, stream>>>(
        xq2, w2q, rs2, wsc2, b2, (void*)out, TOK, DIM, INNER);
}

// Round 4
// 423.688 us; speedup vs baseline: 1.0367x; 1.0352x over previous
//
#include <hip/hip_runtime.h>

#define TOK   16384
#define DIM   1024
#define INNER 4096
#define EPSF  1e-5f

typedef int v4i  __attribute__((ext_vector_type(4)));
typedef int v16i __attribute__((ext_vector_type(16)));

static __device__ __forceinline__ void async_copy16(const char* g, char* l) {
    __builtin_amdgcn_global_load_lds(
        (const __attribute__((address_space(1))) unsigned int*)g,
        (__attribute__((address_space(3))) unsigned int*)l, 16, 0, 0);
}

static __device__ __forceinline__ float bf2f(unsigned short u) {
    return __uint_as_float(((unsigned)u) << 16);
}
static __device__ __forceinline__ unsigned short f2bf(float f) {
    unsigned u = __float_as_uint(f);
    return (unsigned short)((u + 0x7fffu + ((u >> 16) & 1u)) >> 16);  // RNE
}

// erf via Abramowitz-Stegun 7.1.26, |abs err| <= 1.5e-7
static __device__ __forceinline__ float fast_erf(float z) {
    float az = fabsf(z);
    float tt = __builtin_amdgcn_rcpf(1.f + 0.3275911f * az);
    float poly = ((((1.061405429f * tt - 1.453152027f) * tt + 1.421413741f) * tt
                   - 0.284496736f) * tt + 0.254829592f) * tt;
    float er = 1.f - poly * __expf(-az * az);
    return copysignf(er, z);
}
static __device__ __forceinline__ float gelu_exact(float v) {
    return 0.5f * v * (1.f + fast_erf(v * 0.70710678118654752f));
}

static __device__ __forceinline__ float waveSum(float v) {
#pragma unroll
    for (int o = 32; o > 0; o >>= 1) v += __shfl_down(v, o, 64);
    return v;
}
static __device__ __forceinline__ float waveMax(float v) {
#pragma unroll
    for (int o = 32; o > 0; o >>= 1) v = fmaxf(v, __shfl_down(v, o, 64));
    return v;
}

// ---- per-tensor sum(|w|) reduction (f32 in) ----
__global__ void absmean_k(const float* __restrict__ w, int n4, float* __restrict__ acc) {
    int idx = blockIdx.x * blockDim.x + threadIdx.x;
    int stride = gridDim.x * blockDim.x;
    const float4* w4 = (const float4*)w;
    float s = 0.f;
    for (int i = idx; i < n4; i += stride) {
        float4 v = w4[i];
        s += fabsf(v.x) + fabsf(v.y) + fabsf(v.z) + fabsf(v.w);
    }
    __shared__ float sp[4];
    int wv = threadIdx.x >> 6, lane = threadIdx.x & 63;
    s = waveSum(s);
    if (lane == 0) sp[wv] = s;
    __syncthreads();
    if (threadIdx.x == 0) atomicAdd(acc, sp[0] + sp[1] + sp[2] + sp[3]);
}

// ---- per-tensor ternary quantize: wq = clip(round(w/clip(mean|w|,eps)),-1,1) ----
__global__ void wquant_k(const float* __restrict__ w, int n,
                         const float* __restrict__ acc, float* __restrict__ wscale,
                         char* __restrict__ wq) {
    float mean = *acc / (float)n;
    float cl = fmaxf(mean, EPSF);
    float s = 1.f / cl;
    if (blockIdx.x == 0 && threadIdx.x == 0) *wscale = cl;  // dequant factor
    int idx = blockIdx.x * blockDim.x + threadIdx.x;
    int stride = gridDim.x * blockDim.x;
    int n4 = n >> 2;
    const float4* w4 = (const float4*)w;
    unsigned* q4 = (unsigned*)wq;
    for (int i = idx; i < n4; i += stride) {
        float4 v = w4[i];
        float e[4] = {v.x, v.y, v.z, v.w};
        unsigned packed = 0;
#pragma unroll
        for (int j = 0; j < 4; j++) {
            float r = rintf(e[j] * s);
            r = fminf(fmaxf(r, -1.f), 1.f);
            packed |= ((unsigned)((int)r & 0xff)) << (8 * j);
        }
        q4[i] = packed;
    }
}

// ---- RMSNorm + per-token absmax int8 quant, f32 input. One block per row. ----
template <int D, int VPT>
__global__ void actquant_f32_k(const float* __restrict__ X, char* __restrict__ Q,
                               float* __restrict__ rs_out) {
    int token = blockIdx.x;
    int t = threadIdx.x;
    const float4* xp = (const float4*)(X + (long)token * D);
    float vals[VPT];
    float ss = 0.f, am = 0.f;
#pragma unroll
    for (int j = 0; j < VPT / 4; j++) {
        float4 v = xp[t * (VPT / 4) + j];
        vals[4 * j] = v.x; vals[4 * j + 1] = v.y; vals[4 * j + 2] = v.z; vals[4 * j + 3] = v.w;
        ss += v.x * v.x + v.y * v.y + v.z * v.z + v.w * v.w;
        am = fmaxf(am, fmaxf(fmaxf(fabsf(v.x), fabsf(v.y)), fmaxf(fabsf(v.z), fabsf(v.w))));
    }
    __shared__ float sp[8];
    __shared__ float bc[2];
    int wv = t >> 6, lane = t & 63;
    float S = waveSum(ss);
    float M = waveMax(am);
    if (lane == 0) { sp[wv] = S; sp[4 + wv] = M; }
    __syncthreads();
    if (t == 0) {
        float Sa = sp[0] + sp[1] + sp[2] + sp[3];
        float Ma = fmaxf(fmaxf(sp[4], sp[5]), fmaxf(sp[6], sp[7]));
        float rinv = rsqrtf(Sa * (1.f / (float)D) + EPSF);   // rsqrt(mean(x^2)+eps)
        float amn = Ma * rinv;                                // absmax of normalized row
        float scale = 127.f / fmaxf(amn, EPSF);
        rs_out[token] = 1.f / scale;                          // dequant factor
        bc[0] = rinv; bc[1] = scale;
    }
    __syncthreads();
    float rinv = bc[0], scale = bc[1];
    unsigned outw[VPT / 4];
#pragma unroll
    for (int j = 0; j < VPT; j++) {
        float r = rintf((vals[j] * rinv) * scale);
        r = fminf(fmaxf(r, -128.f), 127.f);
        unsigned qi = (unsigned)((int)r & 0xff) << (8 * (j & 3));
        if ((j & 3) == 0) outw[j / 4] = qi; else outw[j / 4] |= qi;
    }
    unsigned* qp = (unsigned*)(Q + (long)token * D);
#pragma unroll
    for (int j = 0; j < VPT / 4; j++) qp[t * (VPT / 4) + j] = outw[j];
}

// ---- GELU + RMSNorm + int8 quant, bf16 input (pre-activation h). ----
template <int D, int VPT>  // VPT must be 16
__global__ void actquant_bf16_k(const unsigned short* __restrict__ X, char* __restrict__ Q,
                                float* __restrict__ rs_out) {
    int token = blockIdx.x;
    int t = threadIdx.x;
    const uint4* xp = (const uint4*)(X + (long)token * D);
    float vals[VPT];
    float ss = 0.f, am = 0.f;
#pragma unroll
    for (int j = 0; j < VPT / 8; j++) {
        uint4 v = xp[t * (VPT / 8) + j];
        unsigned ws[4] = {v.x, v.y, v.z, v.w};
#pragma unroll
        for (int p = 0; p < 4; p++) {
            float f0 = gelu_exact(bf2f((unsigned short)(ws[p] & 0xffff)));
            float f1 = gelu_exact(bf2f((unsigned short)(ws[p] >> 16)));
            vals[8 * j + 2 * p] = f0; vals[8 * j + 2 * p + 1] = f1;
            ss += f0 * f0 + f1 * f1;
            am = fmaxf(am, fmaxf(fabsf(f0), fabsf(f1)));
        }
    }
    __shared__ float sp[8];
    __shared__ float bc[2];
    int wv = t >> 6, lane = t & 63;
    float S = waveSum(ss);
    float M = waveMax(am);
    if (lane == 0) { sp[wv] = S; sp[4 + wv] = M; }
    __syncthreads();
    if (t == 0) {
        float Sa = sp[0] + sp[1] + sp[2] + sp[3];
        float Ma = fmaxf(fmaxf(sp[4], sp[5]), fmaxf(sp[6], sp[7]));
        float rinv = rsqrtf(Sa * (1.f / (float)D) + EPSF);
        float amn = Ma * rinv;
        float scale = 127.f / fmaxf(amn, EPSF);
        rs_out[token] = 1.f / scale;
        bc[0] = rinv; bc[1] = scale;
    }
    __syncthreads();
    float rinv = bc[0], scale = bc[1];
    unsigned outw[4];
#pragma unroll
    for (int j = 0; j < VPT; j++) {
        float r = rintf((vals[j] * rinv) * scale);
        r = fminf(fmaxf(r, -128.f), 127.f);
        unsigned qi = (unsigned)((int)r & 0xff) << (8 * (j & 3));
        if ((j & 3) == 0) outw[j / 4] = qi; else outw[j / 4] |= qi;
    }
    uint4* qp = (uint4*)(Q + (long)token * D);
    qp[t] = make_uint4(outw[0], outw[1], outw[2], outw[3]);
}

// ---- int8 GEMM: 256x256 tile, BK=128, 512 thr (8 waves 2Mx4N), 4-phase ----
// = R1's proven-family phase schedule + R3's measured-0-conflict stripe layout.
//
// LDS per tile (A or B): 2 k-half regions of 16 KB, each in stripe form:
// stripe = 16 rows x 64 B; byte(row,slot) = (row>>4)*1024 + slot*256 + (row&15)*16.
// Staging lane l of a wave covers (row = s*16 + (l&15), slot = l>>4) whose stripe
// byte == l*16 -> LINEAR gload_lds dest, row-major coalesced source (16 rows x
// 64 B segments). Fragment read (fixed slot, 32 rows) = 2 contiguous 256-B runs
// -> 0 conflicts (measured in R3).
//
// Schedule: 4 phases per K-tile, one per k-step:
//   phase ks: { 6 ds_read ; [ks<2: issue 4 of T+1's 8 stage loads] ; barrier ;
//               setprio(1) ; 8 MFMA ; setprio(0) ; [ks==3: vmcnt(0)] ; barrier }
// All of T+1's loads issue at phases 0-1, so the end-of-tile vmcnt(0) waits on
// loads ~2.5 phases (>1100 cyc) old -> no latency stall (early-issue replaces
// counted-vmcnt; double buffer makes issue-before-read-done impossible).
// Per CU per tile: LDS 256 KB = 2000 cyc < MFMA 2340 cyc -> matrix-bound.
template <int OUT_F32>
__global__ __launch_bounds__(512, 2) void gemm8p_k(
    const char* __restrict__ A, const char* __restrict__ Bw,
    const float* __restrict__ rs, const float* __restrict__ wscale_p,
    const float* __restrict__ bias, void* __restrict__ outp,
    int M, int N, int K) {
    __shared__ char L[131072];  // A: 2 bufs x 32 KB at 0; B: same at 65536
    int t = threadIdx.x;
    int lane = t & 63, wv = t >> 6;
    int l31 = lane & 31, kh = lane >> 5;
    int wmi = wv >> 2, wni = wv & 3;  // wave tile rows wmi*128+[0,128), cols wni*64+[0,64)

    // XCD-chunked swizzle (grid sizes are multiples of 8)
    int gx = gridDim.x;
    int nwg = gx * gridDim.y;
    int bid = blockIdx.y * gx + blockIdx.x;
    int swz = (bid & 7) * (nwg >> 3) + (bid >> 3);
    int bx = swz % gx, by = swz / gx;
    int m0 = by * 256, n0 = bx * 256;

    // staging: lane covers rows (l&15) of a 16-row stripe, 16-B slot (l>>4);
    // wave wv stages stripes {wv, wv+8} per (matrix, k-half).
    const char* srcA = A  + (long)(m0 + (lane & 15)) * K + ((lane >> 4) * 16);
    const char* srcB = Bw + (long)(n0 + (lane & 15)) * K + ((lane >> 4) * 16);
    char* dstA = L + lane * 16;
    char* dstB = L + 65536 + lane * 16;
    int sA = wv, sB = wv + 8;

    auto stA = [&](int Tt, int kb, int s) {
        async_copy16(srcA + (long)(s * 16) * K + kb * 64 + ((long)Tt << 7),
                     dstA + (Tt & 1) * 32768 + kb * 16384 + s * 1024);
    };
    auto stB = [&](int Tt, int kb, int s) {
        async_copy16(srcB + (long)(s * 16) * K + kb * 64 + ((long)Tt << 7),
                     dstB + (Tt & 1) * 32768 + kb * 16384 + s * 1024);
    };

    // fragment row offsets within a k-half region
    int rA4[4], rB2[2];
#pragma unroll
    for (int i = 0; i < 4; i++) {
        int r = wmi * 128 + i * 32 + l31;
        rA4[i] = (r >> 4) * 1024 + (r & 15) * 16;
    }
#pragma unroll
    for (int j = 0; j < 2; j++) {
        int r = wni * 64 + j * 32 + l31;
        rB2[j] = (r >> 4) * 1024 + (r & 15) * 16;
    }
    int khoff = kh * 256;

    v16i acc[4][2] = {};
    int nK = K >> 7;

    // prologue: full T0 stage (8 loads/thread), drain, barrier
    stA(0, 0, sA); stA(0, 0, sB); stB(0, 0, sA); stB(0, 0, sB);
    stA(0, 1, sA); stA(0, 1, sB); stB(0, 1, sA); stB(0, 1, sB);
    asm volatile("s_waitcnt vmcnt(0)" ::: "memory");
    asm volatile("s_barrier" ::: "memory");

    for (int T = 0; T < nK; ++T) {
        int bo = (T & 1) * 32768;
        bool pre = (T + 1 < nK);
#pragma unroll
        for (int ks = 0; ks < 4; ++ks) {
            // k-slot -> (k-half, 16B slot within 64 B): kb = ks>>1, slot = (ks&1)*2 + kh
            int so = (ks >> 1) * 16384 + (ks & 1) * 512 + khoff;
            const char* pA = L + bo + so;
            const char* pB = L + 65536 + bo + so;
            v4i a0 = *(const v4i*)(pA + rA4[0]);
            v4i a1 = *(const v4i*)(pA + rA4[1]);
            v4i a2 = *(const v4i*)(pA + rA4[2]);
            v4i a3 = *(const v4i*)(pA + rA4[3]);
            v4i b0 = *(const v4i*)(pB + rB2[0]);
            v4i b1 = *(const v4i*)(pB + rB2[1]);
            if (pre) {
                if (ks == 0) { stA(T + 1, 0, sA); stA(T + 1, 0, sB);
                               stB(T + 1, 0, sA); stB(T + 1, 0, sB); }
                else if (ks == 1) { stA(T + 1, 1, sA); stA(T + 1, 1, sB);
                                    stB(T + 1, 1, sA); stB(T + 1, 1, sB); }
            }
            asm volatile("s_barrier" ::: "memory");
            __builtin_amdgcn_s_setprio(1);
            acc[0][0] = __builtin_amdgcn_mfma_i32_32x32x32_i8(a0, b0, acc[0][0], 0, 0, 0);
            acc[0][1] = __builtin_amdgcn_mfma_i32_32x32x32_i8(a0, b1, acc[0][1], 0, 0, 0);
            acc[1][0] = __builtin_amdgcn_mfma_i32_32x32x32_i8(a1, b0, acc[1][0], 0, 0, 0);
            acc[1][1] = __builtin_amdgcn_mfma_i32_32x32x32_i8(a1, b1, acc[1][1], 0, 0, 0);
            acc[2][0] = __builtin_amdgcn_mfma_i32_32x32x32_i8(a2, b0, acc[2][0], 0, 0, 0);
            acc[2][1] = __builtin_amdgcn_mfma_i32_32x32x32_i8(a2, b1, acc[2][1], 0, 0, 0);
            acc[3][0] = __builtin_amdgcn_mfma_i32_32x32x32_i8(a3, b0, acc[3][0], 0, 0, 0);
            acc[3][1] = __builtin_amdgcn_mfma_i32_32x32x32_i8(a3, b1, acc[3][1], 0, 0, 0);
            __builtin_amdgcn_s_setprio(0);
            if (ks == 3) asm volatile("s_waitcnt vmcnt(0)" ::: "memory");
            asm volatile("s_barrier" ::: "memory");
        }
    }

    // Epilogue. 32x32 C/D layout: col = lane&31, row = (reg&3) + 8*(reg>>2) + 4*(lane>>5)
    float wsc = *wscale_p;
    float bv[2];
#pragma unroll
    for (int j = 0; j < 2; j++) bv[j] = bias[n0 + wni * 64 + j * 32 + l31];
#pragma unroll
    for (int i = 0; i < 4; i++) {
        int mbase = m0 + wmi * 128 + i * 32 + 4 * kh;
        float fsv[16];
#pragma unroll
        for (int rg = 0; rg < 16; rg++)
            fsv[rg] = rs[mbase + (rg & 3) + 8 * (rg >> 2)] * wsc;
#pragma unroll
        for (int j = 0; j < 2; j++) {
            int ng = n0 + wni * 64 + j * 32 + l31;
#pragma unroll
            for (int rg = 0; rg < 16; rg++) {
                int mg = mbase + (rg & 3) + 8 * (rg >> 2);
                float v = (float)acc[i][j][rg] * fsv[rg] + bv[j];
                long idx = (long)mg * N + ng;
                if (OUT_F32) ((float*)outp)[idx] = v;
                else ((unsigned short*)outp)[idx] = f2bf(v);
            }
        }
    }
}

extern "C" void kernel_launch(void* const* d_in, const int* in_sizes, int n_in,
                              void* d_out, int out_size, void* d_ws, size_t ws_size,
                              hipStream_t stream) {
    const float* x  = (const float*)d_in[0];
    const float* w1 = (const float*)d_in[1];
    const float* b1 = (const float*)d_in[2];
    const float* w2 = (const float*)d_in[3];
    const float* b2 = (const float*)d_in[4];
    float* out = (float*)d_out;

    char* ws = (char*)d_ws;
    float* acc1 = (float*)(ws + 0);
    float* acc2 = (float*)(ws + 4);
    float* wsc1 = (float*)(ws + 8);
    float* wsc2 = (float*)(ws + 12);
    size_t off = 256;
    char* w1q = ws + off; off += (size_t)INNER * DIM;        // 4 MB
    char* w2q = ws + off; off += (size_t)INNER * DIM;        // 4 MB
    char* xq1 = ws + off; off += (size_t)TOK * DIM;          // 16 MB
    float* rs1 = (float*)(ws + off); off += (size_t)TOK * 4; // 64 KB
    char* xq2 = ws + off; off += (size_t)TOK * INNER;        // 64 MB
    float* rs2 = (float*)(ws + off); off += (size_t)TOK * 4; // 64 KB
    unsigned short* h = (unsigned short*)(ws + off);         // 128 MB bf16 (pre-GELU)

    hipMemsetAsync(d_ws, 0, 16, stream);

    int nw = INNER * DIM;
    absmean_k<<<1024, 256, 0, stream>>>(w1, nw / 4, acc1);
    absmean_k<<<1024, 256, 0, stream>>>(w2, nw / 4, acc2);
    wquant_k<<<2048, 256, 0, stream>>>(w1, nw, acc1, wsc1, w1q);
    wquant_k<<<2048, 256, 0, stream>>>(w2, nw, acc2, wsc2, w2q);

    actquant_f32_k<DIM, 4><<<TOK, 256, 0, stream>>>(x, xq1, rs1);
    gemm8p_k<0><<<dim3(INNER / 256, TOK / 256), 512, 0, stream>>>(
        xq1, w1q, rs1, wsc1, b1, (void*)h, TOK, INNER, DIM);
    actquant_bf16_k<INNER, 16><<<TOK, 256, 0, stream>>>(h, xq2, rs2);
    gemm8p_k<1><<<dim3(DIM / 256, TOK / 256), 512, 0, stream>>>(
        xq2, w2q, rs2, wsc2, b2, (void*)out, TOK, DIM, INNER);
}